// Round 7
// baseline (330.525 us; speedup 1.0000x reference)
//
#include <hip/hip_runtime.h>
#include <math.h>

// ---------------------------------------------------------------------------
// CausalHFPLayer: B=4, N=4096, D=1024, C=64 -> nc=64 chunks/batch, BC=256
// rfft bins M=33, k_low=4, high bins 29. NH=16, NKV=4, HD=64, T=256.
// Round 11: MLP fix in the transform kernels. dft/irfft staged their B-tiles
// as 8 rounds of {8 column loads -> convert -> ds_write} = 8 serialized HBM
// round-trips (R6 counters: 49us with ALL pipes <20% = latency-bound).
// Now: hoist ALL column loads (64 fp32 / 57 bf16) into registers first
// (static unrolled indexing -> VGPRs), single wait, then convert+write.
// Everything else identical to R6 (gemm256_high 49us, gemm128s, attn).
// ---------------------------------------------------------------------------

typedef __bf16 bf16_t;
typedef bf16_t bf16x8 __attribute__((ext_vector_type(8)));
typedef float f32x4 __attribute__((ext_vector_type(4)));

#define EP_NONE 0
#define EP_SIGMOID 1
#define EP_FUSELOW 2
#define EP_HIGH 3

// async global->LDS 16B copy. LDS dest is wave-uniform base + lane*16, so the
// lds pointer must be identical across the wave's lanes (m104/m108).
__device__ __forceinline__ void gld_lds16(const bf16_t* g, bf16_t* l) {
  __builtin_amdgcn_global_load_lds(
      (const __attribute__((address_space(1))) unsigned int*)g,
      (__attribute__((address_space(3))) unsigned int*)l, 16, 0, 0);
}

// =============== weight prep: concat qkv + 4x fp32->bf16 ===================
__global__ __launch_bounds__(256) void prep_w(
    const float* __restrict__ qw, const float* __restrict__ kw,
    const float* __restrict__ vw, const float* __restrict__ ow,
    const float* __restrict__ gw, const float* __restrict__ pwr,
    const float* __restrict__ pwi, bf16_t* __restrict__ Wqkv,
    bf16_t* __restrict__ owb, bf16_t* __restrict__ gwb,
    bf16_t* __restrict__ pwrb, bf16_t* __restrict__ pwib) {
  int gi = blockIdx.x * 256 + threadIdx.x;
  float4 v;
  bf16_t* o;
  if (gi < 393216) {
    if (gi < 262144) v = ((const float4*)qw)[gi];
    else if (gi < 327680) v = ((const float4*)kw)[gi - 262144];
    else v = ((const float4*)vw)[gi - 327680];
    o = Wqkv + (long)gi * 4;
  } else {
    int j = gi - 393216;
    int sel = j >> 18, off = j & 262143;
    const float* s = sel == 0 ? ow : sel == 1 ? gw : sel == 2 ? pwr : pwi;
    bf16_t* d = sel == 0 ? owb : sel == 1 ? gwb : sel == 2 ? pwrb : pwib;
    v = ((const float4*)s)[off];
    o = d + (long)off * 4;
  }
  o[0] = (bf16_t)v.x; o[1] = (bf16_t)v.y; o[2] = (bf16_t)v.z; o[3] = (bf16_t)v.w;
}

// ====================== fft basis tables (constant) ========================
// PLAIN layout (r*64+k): kernels load fragments directly from global into
// registers (frag for (row,s,q) = elements k in [(s*4+q)*8, +8) of row).
// dft basis D[80 r][64 k]: r<33 cos, 33..65 -sin, 66..79 zero. bf16 hi+res.
// irfft basis T[64 t][64 k] (k: 0..28 Rf f=4..32; 29..56 If f=4..31; pad).
// Tlow[64][8] fp32 low-bin basis.
__global__ __launch_bounds__(256) void mk_basis(bf16_t* __restrict__ dhi,
                                                bf16_t* __restrict__ dres,
                                                bf16_t* __restrict__ bhi,
                                                bf16_t* __restrict__ bres,
                                                float* __restrict__ tlow) {
  int idx = blockIdx.x * 256 + threadIdx.x;
  const float TW = 6.283185307179586f / 64.f;
  if (idx < 5120) {  // dft basis
    int r = idx >> 6, k = idx & 63;
    float v = 0.f;
    if (r < 33) {
      v = cosf(TW * (float)((r * k) & 63));
    } else if (r < 66) {
      v = -sinf(TW * (float)(((r - 33) * k) & 63));
    }
    bf16_t h = (bf16_t)v;
    float res = v - (float)h;
    dhi[idx] = h;
    dres[idx] = (bf16_t)res;
  } else if (idx < 9216) {  // irfft basis
    int i = idx - 5120;
    int t = i >> 6, k = i & 63;
    float v = 0.f;
    if (k < 28) {
      int ft = ((4 + k) * t) & 63;
      v = 2.f * cosf(TW * (float)ft) * (1.f / 64.f);
    } else if (k == 28) {  // f=32 Nyquist: single-counted
      int ft = (32 * t) & 63;
      v = cosf(TW * (float)ft) * (1.f / 64.f);
    } else if (k < 57) {
      int ft = ((k - 25) * t) & 63;
      v = -2.f * sinf(TW * (float)ft) * (1.f / 64.f);
    }
    bf16_t h = (bf16_t)v;
    float res = v - (float)h;
    bhi[i] = h;
    bres[i] = (bf16_t)res;
  } else if (idx < 9728) {  // tlow
    int i = idx - 9216;
    int t = i >> 3, j = i & 7;
    float v = 0.f;
    if (j == 0) v = 1.f / 64.f;
    else if (j < 7) {
      int f = (j + 1) >> 1;  // 1,1,2,2,3,3
      int ft = (f * t) & 63;
      float th = TW * (float)ft;
      v = (j & 1) ? 2.f * cosf(th) * (1.f / 64.f)
                  : -2.f * sinf(th) * (1.f / 64.f);
    }
    tlow[i] = v;
  }
}

// ========================= DFT (rfft) via MFMA =============================
// Xh[bc][r][d] (r<33 real, 33..65 imag) = sum_t D[r][t] * x[bc][t][d].
// Block: one bc x 128 d-cols, 2 waves, 32KB LDS -> 5 blocks/CU. Basis hi+res
// direct from global (L1-resident, frag layout). Data hi+res in LDS with XOR
// slot swizzle; ALL 64 column loads hoisted to registers (1 HBM round-trip).
__global__ __launch_bounds__(128) void dft_mfma(
    const float* __restrict__ X, const bf16_t* __restrict__ dhi,
    const bf16_t* __restrict__ dres, bf16_t* __restrict__ Xh,
    bf16_t* __restrict__ XLr, bf16_t* __restrict__ XLi,
    bf16_t* __restrict__ gmean) {
  const int bc = blockIdx.y;        // 0..255
  const int d0 = blockIdx.x * 128;  // 8 d-tiles
  const int tid = threadIdx.x;      // 0..127
  const int lane = tid & 63, wave = tid >> 6;
  const int mr = lane & 15, q = lane >> 4;
  const int wn = wave * 64;

  __shared__ bf16_t Bh[128 * 64];
  __shared__ bf16_t Br[128 * 64];

  // B transpose-stage: thread owns d-col (d0+tid). Hoist all 64 loads into
  // registers (independent, issue back-to-back -> single latency exposure),
  // then convert hi/res + ds_write_b128 with XOR slot swizzle (g ^ (tid&7)).
  {
    const float* xc = X + ((long)bc * 64) * 1024 + d0 + tid;
    float xv[64];
#pragma unroll
    for (int t = 0; t < 64; t++) xv[t] = xc[(long)t * 1024];
    const int sw = tid & 7;
#pragma unroll
    for (int g = 0; g < 8; g++) {
      bf16x8 vh, vr;
#pragma unroll
      for (int i = 0; i < 8; i++) {
        float v = xv[g * 8 + i];
        bf16_t h = (bf16_t)v;
        vh[i] = h;
        vr[i] = (bf16_t)(v - (float)h);
      }
      *(bf16x8*)&Bh[tid * 64 + ((g ^ sw) << 3)] = vh;
      *(bf16x8*)&Br[tid * 64 + ((g ^ sw) << 3)] = vr;
    }
  }
  __syncthreads();  // ds_writes complete

  f32x4 acc[5][4];
#pragma unroll
  for (int i = 0; i < 5; i++)
#pragma unroll
    for (int j = 0; j < 4; j++) acc[i][j] = (f32x4){0.f, 0.f, 0.f, 0.f};

#pragma unroll
  for (int s = 0; s < 2; s++) {
    bf16x8 bh[4], br[4];
#pragma unroll
    for (int ni = 0; ni < 4; ni++) {
      int dcol = wn + ni * 16 + mr;
      int so = (((s * 4 + q) ^ (dcol & 7)) << 3);
      bh[ni] = *(const bf16x8*)&Bh[dcol * 64 + so];
      br[ni] = *(const bf16x8*)&Br[dcol * 64 + so];
    }
#pragma unroll
    for (int mi = 0; mi < 5; mi++) {
      int trow = mi * 16 + mr;
      // basis frag direct from global (plain layout, frag = 16B at
      // trow*64 + (s*4+q)*8)
      bf16x8 ah = *(const bf16x8*)&dhi[trow * 64 + (s * 4 + q) * 8];
      bf16x8 ar = *(const bf16x8*)&dres[trow * 64 + (s * 4 + q) * 8];
#pragma unroll
      for (int ni = 0; ni < 4; ni++) {
        acc[mi][ni] = __builtin_amdgcn_mfma_f32_16x16x32_bf16(
            ah, bh[ni], acc[mi][ni], 0, 0, 0);
        acc[mi][ni] = __builtin_amdgcn_mfma_f32_16x16x32_bf16(
            ah, br[ni], acc[mi][ni], 0, 0, 0);
        acc[mi][ni] = __builtin_amdgcn_mfma_f32_16x16x32_bf16(
            ar, bh[ni], acc[mi][ni], 0, 0, 0);
      }
    }
  }

  const int b = bc >> 6, ch = bc & 63;
  bf16_t* xp = Xh + (long)bc * 66 * 1024 + d0;
#pragma unroll
  for (int mi = 0; mi < 5; mi++) {
#pragma unroll
    for (int r = 0; r < 4; r++) {
      int row = mi * 16 + q * 4 + r;
      if (row >= 66) continue;
#pragma unroll
      for (int ni = 0; ni < 4; ni++) {
        int col = wn + ni * 16 + mr;
        float val = acc[mi][ni][r];
        xp[(long)row * 1024 + col] = (bf16_t)val;
        if (row == 0)
          gmean[(long)bc * 1024 + d0 + col] = (bf16_t)(val * (1.f / 64.f));
        if (row < 4)
          XLr[((long)(b * 256 + ch * 4 + row)) * 1024 + d0 + col] = (bf16_t)val;
        if (row >= 33 && row < 37)
          XLi[((long)(b * 256 + ch * 4 + row - 33)) * 1024 + d0 + col] =
              (bf16_t)val;
      }
    }
  }
}

// ================== 128^2 pipelined GEMM (small-M epilogues) ===============
// C[M,N] = A[M,K=1024] @ B[N,K]^T. 256 threads = 4 waves (2M x 2N), per-wave
// 64x64 out. 4-slot LDS ring (64KB), depth-3 prefetch, counted vmcnt.
// 1D grid with XCD swizzle (grids all multiples of 8 -> bijective).
template <int EMODE>
__global__ __launch_bounds__(256, 2) void gemm128(
    const bf16_t* __restrict__ A0, const bf16_t* __restrict__ A1,
    const bf16_t* __restrict__ B0, const bf16_t* __restrict__ B1,
    int N, int ntc, int zc,
    void* __restrict__ C0v, void* __restrict__ C1v,
    const bf16_t* __restrict__ E0, const bf16_t* __restrict__ E1,
    const float* __restrict__ alpha_ptr) {
  constexpr int K = 1024;
  constexpr int NT = 32;                  // K/32 K-tiles
  __shared__ bf16_t lds[4][2][128 * 32];  // ring x (A,B) x 8KB = 64KB

  const int nwg = gridDim.x;
  const int g = (blockIdx.x & 7) * (nwg >> 3) + (blockIdx.x >> 3);
  const int per_mt = ntc * zc;
  const int mt = g / per_mt, rem = g - mt * per_mt;
  const int nt = rem % ntc, z = rem / ntc;
  const bf16_t* A = z ? A1 : A0;
  const bf16_t* B = z ? B1 : B0;
  void* Cv = z ? C1v : C0v;
  const bf16_t* E = z ? E1 : E0;
  const int m0 = mt * 128, n0 = nt * 128;

  const int tid = threadIdx.x;
  const int lane = tid & 63, wave = tid >> 6;
  const int wm = (wave & 1) * 64, wn = (wave >> 1) * 64;
  const int q = lane >> 4, mr = lane & 15;
  const int srow = tid >> 2, sk8 = (tid & 3) * 8;

  f32x4 acc[4][4];
#pragma unroll
  for (int i = 0; i < 4; i++)
#pragma unroll
    for (int j = 0; j < 4; j++) acc[i][j] = (f32x4){0.f, 0.f, 0.f, 0.f};

  auto stage = [&](int t) {
    const int bi = t & 3;
    const int kb = t * 32;
#pragma unroll
    for (int it = 0; it < 2; it++) {
      gld_lds16(A + (long)(m0 + it * 64 + srow) * K + kb + sk8,
                &lds[bi][0][(it * 256 + wave * 64) * 8]);
      gld_lds16(B + (long)(n0 + it * 64 + srow) * K + kb + sk8,
                &lds[bi][1][(it * 256 + wave * 64) * 8]);
    }
  };

  stage(0);
  stage(1);
  stage(2);

  for (int t = 0; t < NT; t++) {
    if (t < NT - 2)
      asm volatile("s_waitcnt vmcnt(8)" ::: "memory");
    else if (t == NT - 2)
      asm volatile("s_waitcnt vmcnt(4)" ::: "memory");
    else
      asm volatile("s_waitcnt vmcnt(0)" ::: "memory");
    __builtin_amdgcn_sched_barrier(0);
    __builtin_amdgcn_s_barrier();  // all waves' tile-t LDS writes now visible
    if (t + 3 < NT) stage(t + 3);  // slot freed before this barrier

    const bf16_t* As_ = &lds[t & 3][0][0];
    const bf16_t* Bs_ = &lds[t & 3][1][0];
    bf16x8 bfr[4];
#pragma unroll
    for (int ni = 0; ni < 4; ni++)
      bfr[ni] = *(const bf16x8*)&Bs_[(wn + ni * 16 + mr) * 32 + q * 8];
    __builtin_amdgcn_s_setprio(1);
#pragma unroll
    for (int mi = 0; mi < 4; mi++) {
      bf16x8 af = *(const bf16x8*)&As_[(wm + mi * 16 + mr) * 32 + q * 8];
#pragma unroll
      for (int ni = 0; ni < 4; ni++)
        acc[mi][ni] = __builtin_amdgcn_mfma_f32_16x16x32_bf16(
            af, bfr[ni], acc[mi][ni], 0, 0, 0);
    }
    __builtin_amdgcn_s_setprio(0);
  }

  float alpha = 0.f;
  if constexpr (EMODE == EP_FUSELOW) alpha = 1.f / (1.f + __expf(-alpha_ptr[0]));
#pragma unroll
  for (int mi = 0; mi < 4; mi++) {
#pragma unroll
    for (int ni = 0; ni < 4; ni++) {
      int col = n0 + wn + ni * 16 + mr;
      int rbase = m0 + wm + mi * 16 + q * 4;
#pragma unroll
      for (int r = 0; r < 4; r++) {
        int row = rbase + r;
        float val = acc[mi][ni][r];
        if constexpr (EMODE == EP_NONE) {
          ((bf16_t*)Cv)[(long)row * N + col] = (bf16_t)val;
        } else if constexpr (EMODE == EP_SIGMOID) {
          ((float*)Cv)[(long)row * N + col] = 1.f / (1.f + __expf(-val));
        } else {  // EP_FUSELOW
          float xl = (float)E[(long)row * 1024 + col];
          ((float*)Cv)[(long)row * 1024 + col] = alpha * val + (1.f - alpha) * xl;
        }
      }
    }
  }
}

// ================= 256^2-tile pipelined GEMM for EP_HIGH ===================
// C[7424,1024] = A[7424,1024] @ B[1024,1024]^T, epilogue: Xh high rows
// += C*gate (in place). 512 threads = 8 waves (2M x 4N), per-wave 128x64 out.
// BK=32, 4-slot LDS ring, depth-3 counted-vmcnt prefetch. sigma(r) slot
// swizzle via pre-swizzled global source (R3 version, 49.3us measured).
__global__ __launch_bounds__(512, 2) void gemm256_high(
    const bf16_t* __restrict__ A0, const bf16_t* __restrict__ A1,
    const bf16_t* __restrict__ B0, const bf16_t* __restrict__ B1,
    bf16_t* __restrict__ XhMut, const float* __restrict__ gate) {
  constexpr int K = 1024;
  constexpr int NT = K / 32;  // 32 K-tiles
  __shared__ bf16_t lds[4][2][256 * 32];  // [ring][A|B][row*32+k] = 128 KiB

  const int id = blockIdx.x;                 // 232 blocks
  const int kk = (id & 7) * 29 + (id >> 3);  // bijection [0,232)
  const int mt = kk >> 3, rem = kk & 7;
  const int nt = rem & 3, z = rem >> 2;
  const bf16_t* A = z ? A1 : A0;
  const bf16_t* B = z ? B1 : B0;
  const int imoff = z ? 33 * 1024 : 0;
  const int m0 = mt * 256, n0 = nt * 256;

  const int tid = threadIdx.x;
  const int lane = tid & 63, wave = tid >> 6;
  const int wm = (wave & 1) * 128, wn = (wave >> 1) * 64;
  const int q = lane >> 4, mr = lane & 15;
  const int srow = tid >> 2;
  const int gk8 = (((tid & 3) ^ ((((tid >> 2) & 3) + ((tid >> 4) & 3)) & 3)) << 3);

  f32x4 acc[8][4];
#pragma unroll
  for (int i = 0; i < 8; i++)
#pragma unroll
    for (int j = 0; j < 4; j++) acc[i][j] = (f32x4){0.f, 0.f, 0.f, 0.f};

  auto stage = [&](int t) {
    const int bi = t & 3;
    const int kb = t * 32;
#pragma unroll
    for (int rd = 0; rd < 2; rd++) {
      gld_lds16(A + (long)(m0 + rd * 128 + srow) * K + kb + gk8,
                &lds[bi][0][(rd * 512 + wave * 64) * 8]);
      gld_lds16(B + (long)(n0 + rd * 128 + srow) * K + kb + gk8,
                &lds[bi][1][(rd * 512 + wave * 64) * 8]);
    }
  };

  stage(0);
  stage(1);
  stage(2);

  const int asl = (q ^ (((mr & 3) + ((mr >> 2) & 3)) & 3)) * 8;

  for (int t = 0; t < NT; t++) {
    if (t < NT - 2)
      asm volatile("s_waitcnt vmcnt(8)" ::: "memory");
    else if (t == NT - 2)
      asm volatile("s_waitcnt vmcnt(4)" ::: "memory");
    else
      asm volatile("s_waitcnt vmcnt(0)" ::: "memory");
    __builtin_amdgcn_sched_barrier(0);
    __builtin_amdgcn_s_barrier();
    if (t + 3 < NT) stage(t + 3);

    const bf16_t* As_ = &lds[t & 3][0][0];
    const bf16_t* Bs_ = &lds[t & 3][1][0];
    bf16x8 bfr[4];
#pragma unroll
    for (int ni = 0; ni < 4; ni++)
      bfr[ni] = *(const bf16x8*)&Bs_[(wn + ni * 16 + mr) * 32 + asl];
    __builtin_amdgcn_s_setprio(1);
#pragma unroll
    for (int mi = 0; mi < 8; mi++) {
      bf16x8 af = *(const bf16x8*)&As_[(wm + mi * 16 + mr) * 32 + asl];
#pragma unroll
      for (int ni = 0; ni < 4; ni++)
        acc[mi][ni] = __builtin_amdgcn_mfma_f32_16x16x32_bf16(
            af, bfr[ni], acc[mi][ni], 0, 0, 0);
    }
    __builtin_amdgcn_s_setprio(0);
  }

  // epilogue: Xh[bc][4+l][:] += C * gate[bc][:]  (rows: row = bc*29 + l)
#pragma unroll
  for (int mi = 0; mi < 8; mi++) {
#pragma unroll
    for (int r = 0; r < 4; r++) {
      int row = m0 + wm + mi * 16 + q * 4 + r;
      int bc = row / 29, l = row - bc * 29;
      long xbase = ((long)bc * 66 + 4 + l) * 1024 + imoff;
      const float* gp = gate + (long)bc * 1024;
#pragma unroll
      for (int ni = 0; ni < 4; ni++) {
        int col = n0 + wn + ni * 16 + mr;
        long x = xbase + col;
        XhMut[x] = (bf16_t)fmaf(acc[mi][ni][r], gp[col], (float)XhMut[x]);
      }
    }
  }
}

// ====================== MFMA flash attention ===============================
__global__ __launch_bounds__(256) void attn_mfma(const bf16_t* __restrict__ QKVr,
                                                 const bf16_t* __restrict__ QKVi,
                                                 bf16_t* __restrict__ Or_,
                                                 bf16_t* __restrict__ Oi_) {
  const int h = blockIdx.x;
  const int b = blockIdx.y >> 2, qt = blockIdx.y & 3;
  const bf16_t* QKV = blockIdx.z ? QKVi : QKVr;
  bf16_t* O = blockIdx.z ? Oi_ : Or_;
  const int kvh = h >> 2;
  const int tid = threadIdx.x;
  const int lane = tid & 63, wave = tid >> 6;
  const int mr = lane & 15, q4 = lane >> 4;

  __shared__ bf16_t Ks[64 * 72];
  __shared__ bf16_t Vt[64 * 72];
  __shared__ bf16_t Ps[4][16 * 72];

  bf16x8 af[2];
  {
    const bf16_t* qp =
        QKV + (long)(b * 256 + qt * 64 + wave * 16 + mr) * 1536 + h * 64;
    af[0] = *(const bf16x8*)(qp + q4 * 8);
    af[1] = *(const bf16x8*)(qp + 32 + q4 * 8);
  }
  f32x4 Oacc[4];
#pragma unroll
  for (int ni = 0; ni < 4; ni++) Oacc[ni] = (f32x4){0.f, 0.f, 0.f, 0.f};
  float mrow[4], lrow[4];
#pragma unroll
  for (int r = 0; r < 4; r++) { mrow[r] = -1e30f; lrow[r] = 0.f; }

  for (int kt = 0; kt <= qt; kt++) {
#pragma unroll
    for (int it = 0; it < 2; it++) {
      int idx = tid + it * 256;
      int key = idx >> 3, dg = idx & 7;
      const bf16_t* kp = QKV + (long)(b * 256 + kt * 64 + key) * 1536 + 1024 +
                         kvh * 64 + dg * 8;
      *(bf16x8*)&Ks[key * 72 + dg * 8] = *(const bf16x8*)kp;
      bf16x8 vv = *(const bf16x8*)(kp + 256);
#pragma unroll
      for (int j = 0; j < 8; j++) Vt[(dg * 8 + j) * 72 + key] = vv[j];
    }
    __syncthreads();

    f32x4 S[4];
#pragma unroll
    for (int ni = 0; ni < 4; ni++) {
      S[ni] = (f32x4){0.f, 0.f, 0.f, 0.f};
#pragma unroll
      for (int s = 0; s < 2; s++) {
        bf16x8 kb = *(const bf16x8*)&Ks[(ni * 16 + mr) * 72 + s * 32 + q4 * 8];
        S[ni] = __builtin_amdgcn_mfma_f32_16x16x32_bf16(af[s], kb, S[ni], 0, 0, 0);
      }
    }
#pragma unroll
    for (int ni = 0; ni < 4; ni++) {
#pragma unroll
      for (int r = 0; r < 4; r++) {
        float v = S[ni][r] * 0.125f;
        if (kt == qt) {
          int qrow = wave * 16 + q4 * 4 + r;
          int kcol = ni * 16 + mr;
          if ((qrow >> 2) < (kcol >> 2)) v = -1e30f;
        }
        S[ni][r] = v;
      }
    }
#pragma unroll
    for (int r = 0; r < 4; r++) {
      float mx = fmaxf(fmaxf(S[0][r], S[1][r]), fmaxf(S[2][r], S[3][r]));
#pragma unroll
      for (int off = 1; off < 16; off <<= 1) mx = fmaxf(mx, __shfl_xor(mx, off));
      float mn = fmaxf(mrow[r], mx);
      float sc = __expf(mrow[r] - mn);
      mrow[r] = mn;
      float rs = 0.f;
#pragma unroll
      for (int ni = 0; ni < 4; ni++) {
        float p = __expf(S[ni][r] - mn);
        rs += p;
        Ps[wave][(q4 * 4 + r) * 72 + ni * 16 + mr] = (bf16_t)p;
      }
#pragma unroll
      for (int off = 1; off < 16; off <<= 1) rs += __shfl_xor(rs, off);
      lrow[r] = lrow[r] * sc + rs;
#pragma unroll
      for (int ni = 0; ni < 4; ni++) Oacc[ni][r] *= sc;
    }
    bf16x8 pa[2];
    pa[0] = *(const bf16x8*)&Ps[wave][mr * 72 + q4 * 8];
    pa[1] = *(const bf16x8*)&Ps[wave][mr * 72 + 32 + q4 * 8];
#pragma unroll
    for (int ni = 0; ni < 4; ni++) {
#pragma unroll
      for (int s = 0; s < 2; s++) {
        bf16x8 vb = *(const bf16x8*)&Vt[(ni * 16 + mr) * 72 + s * 32 + q4 * 8];
        Oacc[ni] = __builtin_amdgcn_mfma_f32_16x16x32_bf16(pa[s], vb, Oacc[ni], 0, 0, 0);
      }
    }
    __syncthreads();
  }

#pragma unroll
  for (int r = 0; r < 4; r++) {
    float inv = 1.f / lrow[r];
    long row = b * 256 + qt * 64 + wave * 16 + q4 * 4 + r;
#pragma unroll
    for (int ni = 0; ni < 4; ni++)
      O[row * 1024 + h * 64 + ni * 16 + mr] = (bf16_t)(Oacc[ni][r] * inv);
  }
}

// ===================== depthwise causal conv + GELU ========================
__global__ __launch_bounds__(256) void dwconv_kernel(const bf16_t* __restrict__ Xh,
                                                     const float* __restrict__ dwr,
                                                     const float* __restrict__ dwi,
                                                     bf16_t* __restrict__ Gr,
                                                     bf16_t* __restrict__ Gi) {
  const int d = blockIdx.x * 256 + threadIdx.x;
  const int bc = blockIdx.y;
  const float* dw = blockIdx.z ? dwi : dwr;
  bf16_t* G = blockIdx.z ? Gi : Gr;
  const int imoff = blockIdx.z ? 33 * 1024 : 0;
  float w[7];
#pragma unroll
  for (int j = 0; j < 7; j++) w[j] = dw[d * 7 + j];
  float x[29];
#pragma unroll
  for (int l = 0; l < 29; l++)
    x[l] = (float)Xh[((long)bc * 66 + 4 + l) * 1024 + imoff + d];
#pragma unroll
  for (int l = 0; l < 29; l++) {
    float y = 0.f;
#pragma unroll
    for (int j = 0; j < 7; j++) {
      int src = l - 6 + j;
      if (src >= 0) y = fmaf(w[j], x[src], y);
    }
    float ge = 0.5f * y * (1.f + erff(y * 0.7071067811865475f));
    G[((long)bc * 29 + l) * 1024 + d] = (bf16_t)ge;
  }
}

// ======================= irfft via MFMA + fp32 low =========================
// out[bc*64+t][d] = sum_k T[t][k]*XhHigh[bc][k][d] (basis hi+res direct from
// global in frag layout) + fp32 low-bin part from Af (f=0..3) via Tlow.
// Block: one bc x 128 d-cols, 2 waves, 18KB LDS -> 8 blocks/CU. ALL 57
// column loads hoisted to registers (1 HBM round-trip).
__global__ __launch_bounds__(128) void irfft_mfma(
    const bf16_t* __restrict__ Xh, const float* __restrict__ Afr,
    const float* __restrict__ Afi, const bf16_t* __restrict__ bhi,
    const bf16_t* __restrict__ bres, const float* __restrict__ tlow,
    float* __restrict__ out) {
  const int bc = blockIdx.y;        // 0..255
  const int d0 = blockIdx.x * 128;  // 8 d-tiles
  const int tid = threadIdx.x;      // 0..127
  const int lane = tid & 63, wave = tid >> 6;
  const int mr = lane & 15, q = lane >> 4;
  const int wn = wave * 64;

  __shared__ bf16_t Bs[128 * 64];
  __shared__ float Tl[64 * 8];

  ((float4*)Tl)[tid] = ((const float4*)tlow)[tid];  // 128 x 16B = 2KB

  // B transpose-stage: thread owns d-column (d0+tid); rows k=0..56 map to
  // Xh rows 4..32 (real f=4..32) and 37..64 (imag f=4..31); 57..63 zero.
  // All 57 loads hoisted into registers before any ds_write.
  {
    const bf16_t* xc = Xh + (long)bc * 66 * 1024 + d0 + tid;
    bf16_t xv[57];
#pragma unroll
    for (int j = 0; j < 57; j++) {
      int row = (j < 29) ? (4 + j) : (8 + j);
      xv[j] = xc[(long)row * 1024];
    }
    const int sw = tid & 7;
#pragma unroll
    for (int g = 0; g < 8; g++) {
      bf16x8 v;
#pragma unroll
      for (int i = 0; i < 8; i++) {
        int j = g * 8 + i;
        v[i] = (j < 57) ? xv[j] : (bf16_t)0.f;
      }
      *(bf16x8*)&Bs[tid * 64 + ((g ^ sw) << 3)] = v;
    }
  }
  __syncthreads();  // ds_writes (and Tl) complete

  f32x4 acc[4][4];
#pragma unroll
  for (int i = 0; i < 4; i++)
#pragma unroll
    for (int j = 0; j < 4; j++) acc[i][j] = (f32x4){0.f, 0.f, 0.f, 0.f};

#pragma unroll
  for (int s = 0; s < 2; s++) {
    bf16x8 bfv[4];
#pragma unroll
    for (int ni = 0; ni < 4; ni++) {
      int dcol = wn + ni * 16 + mr;
      bfv[ni] = *(const bf16x8*)&Bs[dcol * 64 + (((s * 4 + q) ^ (dcol & 7)) << 3)];
    }
#pragma unroll
    for (int mi = 0; mi < 4; mi++) {
      int trow = mi * 16 + mr;
      bf16x8 ah = *(const bf16x8*)&bhi[trow * 64 + (s * 4 + q) * 8];
      bf16x8 ar = *(const bf16x8*)&bres[trow * 64 + (s * 4 + q) * 8];
#pragma unroll
      for (int ni = 0; ni < 4; ni++) {
        acc[mi][ni] = __builtin_amdgcn_mfma_f32_16x16x32_bf16(
            ah, bfv[ni], acc[mi][ni], 0, 0, 0);
        acc[mi][ni] = __builtin_amdgcn_mfma_f32_16x16x32_bf16(
            ar, bfv[ni], acc[mi][ni], 0, 0, 0);
      }
    }
  }

  // fp32 low-bin epilogue: rows f=0..3 of Af (alpha-fused), Tlow basis
  const int arow = (bc >> 6) * 256 + (bc & 63) * 4;
  float R[4][7];
#pragma unroll
  for (int ni = 0; ni < 4; ni++) {
    long ab = (long)arow * 1024 + d0 + wn + ni * 16 + mr;
    R[ni][0] = Afr[ab];
    R[ni][1] = Afr[ab + 1024];
    R[ni][2] = Afi[ab + 1024];
    R[ni][3] = Afr[ab + 2048];
    R[ni][4] = Afi[ab + 2048];
    R[ni][5] = Afr[ab + 3072];
    R[ni][6] = Afi[ab + 3072];
  }
  const long obase = ((long)bc * 64) * 1024 + d0;
#pragma unroll
  for (int mi = 0; mi < 4; mi++) {
#pragma unroll
    for (int r = 0; r < 4; r++) {
      int t = mi * 16 + q * 4 + r;
      const float* tl = &Tl[t * 8];
#pragma unroll
      for (int ni = 0; ni < 4; ni++) {
        float low = tl[0] * R[ni][0];
        low = fmaf(tl[1], R[ni][1], low);
        low = fmaf(tl[2], R[ni][2], low);
        low = fmaf(tl[3], R[ni][3], low);
        low = fmaf(tl[4], R[ni][4], low);
        low = fmaf(tl[5], R[ni][5], low);
        low = fmaf(tl[6], R[ni][6], low);
        out[obase + (long)t * 1024 + wn + ni * 16 + mr] = acc[mi][ni][r] + low;
      }
    }
  }
}

// ============================ launcher =====================================
extern "C" void kernel_launch(void* const* d_in, const int* in_sizes, int n_in,
                              void* d_out, int out_size, void* d_ws, size_t ws_size,
                              hipStream_t stream) {
  const float* hidden = (const float*)d_in[0];
  const float* q_w = (const float*)d_in[1];
  const float* k_w = (const float*)d_in[2];
  const float* v_w = (const float*)d_in[3];
  const float* o_w = (const float*)d_in[4];
  const float* dw_r = (const float*)d_in[5];
  const float* pw_r = (const float*)d_in[6];
  const float* dw_i = (const float*)d_in[7];
  const float* pw_i = (const float*)d_in[8];
  const float* gate_w = (const float*)d_in[9];
  const float* alpha_raw = (const float*)d_in[10];
  float* out = (float*)d_out;

  float* ws = (float*)d_ws;
  // fp32 region
  float* Afr = ws;                       // 1024*1024
  float* Afi = Afr + 1048576;
  float* gg = Afi + 1048576;             // 256*1024
  // bf16 region
  bf16_t* bws = (bf16_t*)(gg + 262144);
  bf16_t* Xh = bws;                      // 256*66*1024 = 17,301,504 bf16
  bf16_t* Wqkv_b = Xh + 17301504;        // 1536*1024
  bf16_t* ow_b = Wqkv_b + 1572864;       // 1024*1024
  bf16_t* gw_b = ow_b + 1048576;
  bf16_t* pwr_b = gw_b + 1048576;
  bf16_t* pwi_b = pwr_b + 1048576;
  bf16_t* XLr = pwi_b + 1048576;         // 1024*1024
  bf16_t* XLi = XLr + 1048576;
  bf16_t* gmean = XLi + 1048576;         // 256*1024
  bf16_t* QKVbr = gmean + 262144;        // 1024*1536
  bf16_t* QKVbi = QKVbr + 1572864;
  bf16_t* Obr = QKVbi + 1572864;         // 1024*1024
  bf16_t* Obi = Obr + 1048576;
  bf16_t* Gr = Obi + 1048576;            // 7424*1024
  bf16_t* Gi = Gr + 7602176;
  bf16_t* bhi = Gi + 7602176;            // 64*64 irfft basis hi (plain)
  bf16_t* bres = bhi + 4096;             // 64*64 irfft basis residual
  bf16_t* dbhi = bres + 4096;            // 80*64 dft basis hi (plain)
  bf16_t* dbres = dbhi + 5120;           // 80*64 dft basis residual
  float* tlowp = (float*)(dbres + 5120); // 64*8 fp32

  // 0) basis tables (plain frag layout)
  mk_basis<<<38, 256, 0, stream>>>(dbhi, dbres, bhi, bres, tlowp);
  // 1) rfft via MFMA -> bf16 Xh + bf16 X_low pack + bf16 chunk-mean
  dft_mfma<<<dim3(8, 256), 128, 0, stream>>>(hidden, dbhi, dbres, Xh, XLr,
                                             XLi, gmean);
  // 2) weights -> bf16 (single launch)
  prep_w<<<5632, 256, 0, stream>>>(q_w, k_w, v_w, o_w, gate_w, pw_r, pw_i,
                                   Wqkv_b, ow_b, gw_b, pwr_b, pwi_b);
  // 3) QKV projections (real & imag), bf16 out: M=1024, N=1536, 192 blocks
  gemm128<EP_NONE><<<192, 256, 0, stream>>>(
      XLr, XLi, Wqkv_b, Wqkv_b, 1536, 12, 2, QKVbr, QKVbi, nullptr, nullptr,
      nullptr);
  // 4) gate = sigmoid(mean @ gate_w^T): M=256, N=1024, 16 blocks
  gemm128<EP_SIGMOID><<<16, 256, 0, stream>>>(
      gmean, gmean, gw_b, gw_b, 1024, 8, 1, gg, gg, nullptr, nullptr,
      nullptr);
  // 5) MFMA flash attention (real & imag), bf16 O out
  attn_mfma<<<dim3(16, 16, 2), 256, 0, stream>>>(QKVbr, QKVbi, Obr, Obi);
  // 6) O projection + alpha*A_low + (1-alpha)*X_low -> fp32 Af: 128 blocks
  gemm128<EP_FUSELOW><<<128, 256, 0, stream>>>(
      Obr, Obi, ow_b, ow_b, 1024, 8, 2, Afr, Afi, XLr, XLi, alpha_raw);
  // 7) depthwise causal conv + exact GELU on high bins, bf16 out
  dwconv_kernel<<<dim3(4, 256, 2), 256, 0, stream>>>(Xh, dw_r, dw_i, Gr, Gi);
  // 8) pointwise conv + gate + residual, in-place into Xh high rows
  gemm256_high<<<dim3(232), 512, 0, stream>>>(Gr, Gi, pwr_b, pwi_b, Xh, gg);
  // 9) irfft via MFMA + fp32 low-bin epilogue
  irfft_mfma<<<dim3(8, 256), 128, 0, stream>>>(Xh, Afr, Afi, bhi, bres,
                                               tlowp, out);
}

// Round 8
// 316.609 us; speedup vs baseline: 1.0440x; 1.0440x over previous
//
#include <hip/hip_runtime.h>
#include <math.h>

// ---------------------------------------------------------------------------
// CausalHFPLayer: B=4, N=4096, D=1024, C=64 -> nc=64 chunks/batch, BC=256
// rfft bins M=33, k_low=4, high bins 29. NH=16, NKV=4, HD=64, T=256.
// Round 12: gemm256_high ported to the 8-phase schedule (T3+T4, m201
// template): BK=64, 2x64KB double-buffered K-tiles, 4 sub-phases/K-tile
// {(kslice, m-half)}, per-phase {ds_read frags || stage next tile's halves;
// s_barrier; lgkmcnt(0)+sched_barrier; 16 MFMA @setprio; s_barrier}. XOR
// slot swizzle slot^(row&7) via pre-swizzled global source (rule #21).
// Boundary: vmcnt(0) before phase-4 closing barrier. Everything else = R7
// (R7's gemm256 regression was environment noise: identical code+counters).
// ---------------------------------------------------------------------------

typedef __bf16 bf16_t;
typedef bf16_t bf16x8 __attribute__((ext_vector_type(8)));
typedef float f32x4 __attribute__((ext_vector_type(4)));

#define EP_NONE 0
#define EP_SIGMOID 1
#define EP_FUSELOW 2
#define EP_HIGH 3

// async global->LDS 16B copy. LDS dest is wave-uniform base + lane*16, so the
// lds pointer must be identical across the wave's lanes (m104/m108).
__device__ __forceinline__ void gld_lds16(const bf16_t* g, bf16_t* l) {
  __builtin_amdgcn_global_load_lds(
      (const __attribute__((address_space(1))) unsigned int*)g,
      (__attribute__((address_space(3))) unsigned int*)l, 16, 0, 0);
}

// =============== weight prep: concat qkv + 4x fp32->bf16 ===================
__global__ __launch_bounds__(256) void prep_w(
    const float* __restrict__ qw, const float* __restrict__ kw,
    const float* __restrict__ vw, const float* __restrict__ ow,
    const float* __restrict__ gw, const float* __restrict__ pwr,
    const float* __restrict__ pwi, bf16_t* __restrict__ Wqkv,
    bf16_t* __restrict__ owb, bf16_t* __restrict__ gwb,
    bf16_t* __restrict__ pwrb, bf16_t* __restrict__ pwib) {
  int gi = blockIdx.x * 256 + threadIdx.x;
  float4 v;
  bf16_t* o;
  if (gi < 393216) {
    if (gi < 262144) v = ((const float4*)qw)[gi];
    else if (gi < 327680) v = ((const float4*)kw)[gi - 262144];
    else v = ((const float4*)vw)[gi - 327680];
    o = Wqkv + (long)gi * 4;
  } else {
    int j = gi - 393216;
    int sel = j >> 18, off = j & 262143;
    const float* s = sel == 0 ? ow : sel == 1 ? gw : sel == 2 ? pwr : pwi;
    bf16_t* d = sel == 0 ? owb : sel == 1 ? gwb : sel == 2 ? pwrb : pwib;
    v = ((const float4*)s)[off];
    o = d + (long)off * 4;
  }
  o[0] = (bf16_t)v.x; o[1] = (bf16_t)v.y; o[2] = (bf16_t)v.z; o[3] = (bf16_t)v.w;
}

// ====================== fft basis tables (constant) ========================
// PLAIN layout (r*64+k): kernels load fragments directly from global into
// registers (frag for (row,s,q) = elements k in [(s*4+q)*8, +8) of row).
// dft basis D[80 r][64 k]: r<33 cos, 33..65 -sin, 66..79 zero. bf16 hi+res.
// irfft basis T[64 t][64 k] (k: 0..28 Rf f=4..32; 29..56 If f=4..31; pad).
// Tlow[64][8] fp32 low-bin basis.
__global__ __launch_bounds__(256) void mk_basis(bf16_t* __restrict__ dhi,
                                                bf16_t* __restrict__ dres,
                                                bf16_t* __restrict__ bhi,
                                                bf16_t* __restrict__ bres,
                                                float* __restrict__ tlow) {
  int idx = blockIdx.x * 256 + threadIdx.x;
  const float TW = 6.283185307179586f / 64.f;
  if (idx < 5120) {  // dft basis
    int r = idx >> 6, k = idx & 63;
    float v = 0.f;
    if (r < 33) {
      v = cosf(TW * (float)((r * k) & 63));
    } else if (r < 66) {
      v = -sinf(TW * (float)(((r - 33) * k) & 63));
    }
    bf16_t h = (bf16_t)v;
    float res = v - (float)h;
    dhi[idx] = h;
    dres[idx] = (bf16_t)res;
  } else if (idx < 9216) {  // irfft basis
    int i = idx - 5120;
    int t = i >> 6, k = i & 63;
    float v = 0.f;
    if (k < 28) {
      int ft = ((4 + k) * t) & 63;
      v = 2.f * cosf(TW * (float)ft) * (1.f / 64.f);
    } else if (k == 28) {  // f=32 Nyquist: single-counted
      int ft = (32 * t) & 63;
      v = cosf(TW * (float)ft) * (1.f / 64.f);
    } else if (k < 57) {
      int ft = ((k - 25) * t) & 63;
      v = -2.f * sinf(TW * (float)ft) * (1.f / 64.f);
    }
    bf16_t h = (bf16_t)v;
    float res = v - (float)h;
    bhi[i] = h;
    bres[i] = (bf16_t)res;
  } else if (idx < 9728) {  // tlow
    int i = idx - 9216;
    int t = i >> 3, j = i & 7;
    float v = 0.f;
    if (j == 0) v = 1.f / 64.f;
    else if (j < 7) {
      int f = (j + 1) >> 1;  // 1,1,2,2,3,3
      int ft = (f * t) & 63;
      float th = TW * (float)ft;
      v = (j & 1) ? 2.f * cosf(th) * (1.f / 64.f)
                  : -2.f * sinf(th) * (1.f / 64.f);
    }
    tlow[i] = v;
  }
}

// ========================= DFT (rfft) via MFMA =============================
// Xh[bc][r][d] (r<33 real, 33..65 imag) = sum_t D[r][t] * x[bc][t][d].
// Block: one bc x 128 d-cols, 2 waves, 32KB LDS -> 5 blocks/CU. Basis hi+res
// direct from global (L1-resident, frag layout). Data hi+res in LDS with XOR
// slot swizzle; ALL 64 column loads hoisted to registers (1 HBM round-trip).
__global__ __launch_bounds__(128) void dft_mfma(
    const float* __restrict__ X, const bf16_t* __restrict__ dhi,
    const bf16_t* __restrict__ dres, bf16_t* __restrict__ Xh,
    bf16_t* __restrict__ XLr, bf16_t* __restrict__ XLi,
    bf16_t* __restrict__ gmean) {
  const int bc = blockIdx.y;        // 0..255
  const int d0 = blockIdx.x * 128;  // 8 d-tiles
  const int tid = threadIdx.x;      // 0..127
  const int lane = tid & 63, wave = tid >> 6;
  const int mr = lane & 15, q = lane >> 4;
  const int wn = wave * 64;

  __shared__ bf16_t Bh[128 * 64];
  __shared__ bf16_t Br[128 * 64];

  // B transpose-stage: thread owns d-col (d0+tid). Hoist all 64 loads into
  // registers (independent, issue back-to-back -> single latency exposure),
  // then convert hi/res + ds_write_b128 with XOR slot swizzle (g ^ (tid&7)).
  {
    const float* xc = X + ((long)bc * 64) * 1024 + d0 + tid;
    float xv[64];
#pragma unroll
    for (int t = 0; t < 64; t++) xv[t] = xc[(long)t * 1024];
    const int sw = tid & 7;
#pragma unroll
    for (int g = 0; g < 8; g++) {
      bf16x8 vh, vr;
#pragma unroll
      for (int i = 0; i < 8; i++) {
        float v = xv[g * 8 + i];
        bf16_t h = (bf16_t)v;
        vh[i] = h;
        vr[i] = (bf16_t)(v - (float)h);
      }
      *(bf16x8*)&Bh[tid * 64 + ((g ^ sw) << 3)] = vh;
      *(bf16x8*)&Br[tid * 64 + ((g ^ sw) << 3)] = vr;
    }
  }
  __syncthreads();  // ds_writes complete

  f32x4 acc[5][4];
#pragma unroll
  for (int i = 0; i < 5; i++)
#pragma unroll
    for (int j = 0; j < 4; j++) acc[i][j] = (f32x4){0.f, 0.f, 0.f, 0.f};

#pragma unroll
  for (int s = 0; s < 2; s++) {
    bf16x8 bh[4], br[4];
#pragma unroll
    for (int ni = 0; ni < 4; ni++) {
      int dcol = wn + ni * 16 + mr;
      int so = (((s * 4 + q) ^ (dcol & 7)) << 3);
      bh[ni] = *(const bf16x8*)&Bh[dcol * 64 + so];
      br[ni] = *(const bf16x8*)&Br[dcol * 64 + so];
    }
#pragma unroll
    for (int mi = 0; mi < 5; mi++) {
      int trow = mi * 16 + mr;
      bf16x8 ah = *(const bf16x8*)&dhi[trow * 64 + (s * 4 + q) * 8];
      bf16x8 ar = *(const bf16x8*)&dres[trow * 64 + (s * 4 + q) * 8];
#pragma unroll
      for (int ni = 0; ni < 4; ni++) {
        acc[mi][ni] = __builtin_amdgcn_mfma_f32_16x16x32_bf16(
            ah, bh[ni], acc[mi][ni], 0, 0, 0);
        acc[mi][ni] = __builtin_amdgcn_mfma_f32_16x16x32_bf16(
            ah, br[ni], acc[mi][ni], 0, 0, 0);
        acc[mi][ni] = __builtin_amdgcn_mfma_f32_16x16x32_bf16(
            ar, bh[ni], acc[mi][ni], 0, 0, 0);
      }
    }
  }

  const int b = bc >> 6, ch = bc & 63;
  bf16_t* xp = Xh + (long)bc * 66 * 1024 + d0;
#pragma unroll
  for (int mi = 0; mi < 5; mi++) {
#pragma unroll
    for (int r = 0; r < 4; r++) {
      int row = mi * 16 + q * 4 + r;
      if (row >= 66) continue;
#pragma unroll
      for (int ni = 0; ni < 4; ni++) {
        int col = wn + ni * 16 + mr;
        float val = acc[mi][ni][r];
        xp[(long)row * 1024 + col] = (bf16_t)val;
        if (row == 0)
          gmean[(long)bc * 1024 + d0 + col] = (bf16_t)(val * (1.f / 64.f));
        if (row < 4)
          XLr[((long)(b * 256 + ch * 4 + row)) * 1024 + d0 + col] = (bf16_t)val;
        if (row >= 33 && row < 37)
          XLi[((long)(b * 256 + ch * 4 + row - 33)) * 1024 + d0 + col] =
              (bf16_t)val;
      }
    }
  }
}

// ================== 128^2 pipelined GEMM (small-M epilogues) ===============
// C[M,N] = A[M,K=1024] @ B[N,K]^T. 256 threads = 4 waves (2M x 2N), per-wave
// 64x64 out. 4-slot LDS ring (64KB), depth-3 prefetch, counted vmcnt.
// 1D grid with XCD swizzle (grids all multiples of 8 -> bijective).
template <int EMODE>
__global__ __launch_bounds__(256, 2) void gemm128(
    const bf16_t* __restrict__ A0, const bf16_t* __restrict__ A1,
    const bf16_t* __restrict__ B0, const bf16_t* __restrict__ B1,
    int N, int ntc, int zc,
    void* __restrict__ C0v, void* __restrict__ C1v,
    const bf16_t* __restrict__ E0, const bf16_t* __restrict__ E1,
    const float* __restrict__ alpha_ptr) {
  constexpr int K = 1024;
  constexpr int NT = 32;                  // K/32 K-tiles
  __shared__ bf16_t lds[4][2][128 * 32];  // ring x (A,B) x 8KB = 64KB

  const int nwg = gridDim.x;
  const int g = (blockIdx.x & 7) * (nwg >> 3) + (blockIdx.x >> 3);
  const int per_mt = ntc * zc;
  const int mt = g / per_mt, rem = g - mt * per_mt;
  const int nt = rem % ntc, z = rem / ntc;
  const bf16_t* A = z ? A1 : A0;
  const bf16_t* B = z ? B1 : B0;
  void* Cv = z ? C1v : C0v;
  const bf16_t* E = z ? E1 : E0;
  const int m0 = mt * 128, n0 = nt * 128;

  const int tid = threadIdx.x;
  const int lane = tid & 63, wave = tid >> 6;
  const int wm = (wave & 1) * 64, wn = (wave >> 1) * 64;
  const int q = lane >> 4, mr = lane & 15;
  const int srow = tid >> 2, sk8 = (tid & 3) * 8;

  f32x4 acc[4][4];
#pragma unroll
  for (int i = 0; i < 4; i++)
#pragma unroll
    for (int j = 0; j < 4; j++) acc[i][j] = (f32x4){0.f, 0.f, 0.f, 0.f};

  auto stage = [&](int t) {
    const int bi = t & 3;
    const int kb = t * 32;
#pragma unroll
    for (int it = 0; it < 2; it++) {
      gld_lds16(A + (long)(m0 + it * 64 + srow) * K + kb + sk8,
                &lds[bi][0][(it * 256 + wave * 64) * 8]);
      gld_lds16(B + (long)(n0 + it * 64 + srow) * K + kb + sk8,
                &lds[bi][1][(it * 256 + wave * 64) * 8]);
    }
  };

  stage(0);
  stage(1);
  stage(2);

  for (int t = 0; t < NT; t++) {
    if (t < NT - 2)
      asm volatile("s_waitcnt vmcnt(8)" ::: "memory");
    else if (t == NT - 2)
      asm volatile("s_waitcnt vmcnt(4)" ::: "memory");
    else
      asm volatile("s_waitcnt vmcnt(0)" ::: "memory");
    __builtin_amdgcn_sched_barrier(0);
    __builtin_amdgcn_s_barrier();  // all waves' tile-t LDS writes now visible
    if (t + 3 < NT) stage(t + 3);  // slot freed before this barrier

    const bf16_t* As_ = &lds[t & 3][0][0];
    const bf16_t* Bs_ = &lds[t & 3][1][0];
    bf16x8 bfr[4];
#pragma unroll
    for (int ni = 0; ni < 4; ni++)
      bfr[ni] = *(const bf16x8*)&Bs_[(wn + ni * 16 + mr) * 32 + q * 8];
    __builtin_amdgcn_s_setprio(1);
#pragma unroll
    for (int mi = 0; mi < 4; mi++) {
      bf16x8 af = *(const bf16x8*)&As_[(wm + mi * 16 + mr) * 32 + q * 8];
#pragma unroll
      for (int ni = 0; ni < 4; ni++)
        acc[mi][ni] = __builtin_amdgcn_mfma_f32_16x16x32_bf16(
            af, bfr[ni], acc[mi][ni], 0, 0, 0);
    }
    __builtin_amdgcn_s_setprio(0);
  }

  float alpha = 0.f;
  if constexpr (EMODE == EP_FUSELOW) alpha = 1.f / (1.f + __expf(-alpha_ptr[0]));
#pragma unroll
  for (int mi = 0; mi < 4; mi++) {
#pragma unroll
    for (int ni = 0; ni < 4; ni++) {
      int col = n0 + wn + ni * 16 + mr;
      int rbase = m0 + wm + mi * 16 + q * 4;
#pragma unroll
      for (int r = 0; r < 4; r++) {
        int row = rbase + r;
        float val = acc[mi][ni][r];
        if constexpr (EMODE == EP_NONE) {
          ((bf16_t*)Cv)[(long)row * N + col] = (bf16_t)val;
        } else if constexpr (EMODE == EP_SIGMOID) {
          ((float*)Cv)[(long)row * N + col] = 1.f / (1.f + __expf(-val));
        } else {  // EP_FUSELOW
          float xl = (float)E[(long)row * 1024 + col];
          ((float*)Cv)[(long)row * 1024 + col] = alpha * val + (1.f - alpha) * xl;
        }
      }
    }
  }
}

// ================= 256^2 8-phase pipelined GEMM for EP_HIGH ================
// C[7424,1024] = A @ B^T, epilogue Xh += C*gate (in place). 512 thr = 8 waves
// (2Mx4N), per-wave 128x64. BK=64, double-buffered K-tiles (2x64KB=128KB),
// 16 K-tiles, 4 sub-phases per K-tile (kslice ks, m-half mh). Per phase:
// {ds_read frags (8 or 4 b128) || stage next tile's half-tiles; s_barrier;
// lgkmcnt(0)+sched_barrier (rule #18); 16 MFMA @setprio1; s_barrier}.
// Rows are 128B -> XOR slot swizzle slot^(row&7), applied both-sides
// (rule #21): linear LDS dest, pre-swizzled global source, swizzled read.
// Boundary: all 8 stage loads of t+1 issued in phases 1-2; vmcnt(0) before
// phase-4's closing barrier publishes them; buffers alternate per K-tile.
__global__ __launch_bounds__(512, 2) void gemm256_high(
    const bf16_t* __restrict__ A0, const bf16_t* __restrict__ A1,
    const bf16_t* __restrict__ B0, const bf16_t* __restrict__ B1,
    bf16_t* __restrict__ XhMut, const float* __restrict__ gate) {
  constexpr int K = 1024;
  constexpr int NT = 16;                  // K/64 K-tiles
  __shared__ bf16_t lds[2][2][256 * 64];  // [dbuf][A|B][row*64+k] = 128 KiB

  const int id = blockIdx.x;                 // 232 blocks
  const int kk = (id & 7) * 29 + (id >> 3);  // bijection [0,232)
  const int mt = kk >> 3, rem = kk & 7;
  const int nt = rem & 3, z = rem >> 2;
  const bf16_t* A = (z ? A1 : A0) + (long)(mt * 256) * K;
  const bf16_t* B = (z ? B1 : B0) + (long)(nt * 256) * K;
  const int imoff = z ? 33 * 1024 : 0;
  const int m0 = mt * 256, n0 = nt * 256;

  const int tid = threadIdx.x;
  const int lane = tid & 63, wave = tid >> 6;
  const int wm = (wave & 1) * 128, wn = (wave >> 1) * 64;
  const int q = lane >> 4, mr = lane & 15;
  const int sw = mr & 7;
  const int sl0 = ((q ^ sw) << 3);        // kslice0 swizzled slot (elems)
  const int sl1 = (((4 + q) ^ sw) << 3);  // kslice1

  f32x4 acc[8][4];
#pragma unroll
  for (int i = 0; i < 8; i++)
#pragma unroll
    for (int j = 0; j < 4; j++) acc[i][j] = (f32x4){0.f, 0.f, 0.f, 0.f};

  // stage half h (rows h*128..+128) of matrix mat of K-tile t into dbuf t&1.
  // chunk c = rd*512+tid: row = h*128 + (c>>3); LDS slot c&7 receives global
  // slot (c&7)^(row&7). LDS base wave-uniform + lane*16 (m104).
  auto stage_half = [&](int t, int mat, int h) {
    const bf16_t* src = mat ? B : A;
    bf16_t* dst = &lds[t & 1][mat][0];
    const int kb = t * 64;
#pragma unroll
    for (int rd = 0; rd < 2; rd++) {
      const int c = rd * 512 + tid;
      const int row = h * 128 + (c >> 3);
      const int gs = (c & 7) ^ (row & 7);
      gld_lds16(src + (long)row * K + kb + gs * 8,
                dst + (h * 1024 + rd * 512 + wave * 64) * 8);
    }
  };

  stage_half(0, 0, 0); stage_half(0, 0, 1);
  stage_half(0, 1, 0); stage_half(0, 1, 1);
  asm volatile("s_waitcnt vmcnt(0)" ::: "memory");
  __builtin_amdgcn_sched_barrier(0);
  __builtin_amdgcn_s_barrier();

  for (int t = 0; t < NT; t++) {
    const bf16_t* As_ = &lds[t & 1][0][0];
    const bf16_t* Bs_ = &lds[t & 1][1][0];
    const bool st = (t + 1 < NT);
    bf16x8 afr[4], bfr[4];

    // ---- phase 1: ks=0, mh=0 (+stage A-half0, B-half0 of t+1) ----
#pragma unroll
    for (int i = 0; i < 4; i++) {
      afr[i] = *(const bf16x8*)&As_[(wm + i * 16 + mr) * 64 + sl0];
      bfr[i] = *(const bf16x8*)&Bs_[(wn + i * 16 + mr) * 64 + sl0];
    }
    if (st) { stage_half(t + 1, 0, 0); stage_half(t + 1, 1, 0); }
    __builtin_amdgcn_s_barrier();
    asm volatile("s_waitcnt lgkmcnt(0)" ::: "memory");
    __builtin_amdgcn_sched_barrier(0);
    __builtin_amdgcn_s_setprio(1);
#pragma unroll
    for (int i = 0; i < 4; i++)
#pragma unroll
      for (int n2 = 0; n2 < 4; n2++)
        acc[i][n2] = __builtin_amdgcn_mfma_f32_16x16x32_bf16(
            afr[i], bfr[n2], acc[i][n2], 0, 0, 0);
    __builtin_amdgcn_s_setprio(0);
    __builtin_amdgcn_s_barrier();

    // ---- phase 2: ks=0, mh=1 (+stage A-half1, B-half1 of t+1) ----
#pragma unroll
    for (int i = 0; i < 4; i++)
      afr[i] = *(const bf16x8*)&As_[(wm + (4 + i) * 16 + mr) * 64 + sl0];
    if (st) { stage_half(t + 1, 0, 1); stage_half(t + 1, 1, 1); }
    __builtin_amdgcn_s_barrier();
    asm volatile("s_waitcnt lgkmcnt(0)" ::: "memory");
    __builtin_amdgcn_sched_barrier(0);
    __builtin_amdgcn_s_setprio(1);
#pragma unroll
    for (int i = 0; i < 4; i++)
#pragma unroll
      for (int n2 = 0; n2 < 4; n2++)
        acc[4 + i][n2] = __builtin_amdgcn_mfma_f32_16x16x32_bf16(
            afr[i], bfr[n2], acc[4 + i][n2], 0, 0, 0);
    __builtin_amdgcn_s_setprio(0);
    __builtin_amdgcn_s_barrier();

    // ---- phase 3: ks=1, mh=0 ----
#pragma unroll
    for (int i = 0; i < 4; i++) {
      afr[i] = *(const bf16x8*)&As_[(wm + i * 16 + mr) * 64 + sl1];
      bfr[i] = *(const bf16x8*)&Bs_[(wn + i * 16 + mr) * 64 + sl1];
    }
    __builtin_amdgcn_s_barrier();
    asm volatile("s_waitcnt lgkmcnt(0)" ::: "memory");
    __builtin_amdgcn_sched_barrier(0);
    __builtin_amdgcn_s_setprio(1);
#pragma unroll
    for (int i = 0; i < 4; i++)
#pragma unroll
      for (int n2 = 0; n2 < 4; n2++)
        acc[i][n2] = __builtin_amdgcn_mfma_f32_16x16x32_bf16(
            afr[i], bfr[n2], acc[i][n2], 0, 0, 0);
    __builtin_amdgcn_s_setprio(0);
    __builtin_amdgcn_s_barrier();

    // ---- phase 4: ks=1, mh=1 ; boundary vmcnt before closing barrier ----
#pragma unroll
    for (int i = 0; i < 4; i++)
      afr[i] = *(const bf16x8*)&As_[(wm + (4 + i) * 16 + mr) * 64 + sl1];
    __builtin_amdgcn_s_barrier();
    asm volatile("s_waitcnt lgkmcnt(0)" ::: "memory");
    __builtin_amdgcn_sched_barrier(0);
    __builtin_amdgcn_s_setprio(1);
#pragma unroll
    for (int i = 0; i < 4; i++)
#pragma unroll
      for (int n2 = 0; n2 < 4; n2++)
        acc[4 + i][n2] = __builtin_amdgcn_mfma_f32_16x16x32_bf16(
            afr[i], bfr[n2], acc[4 + i][n2], 0, 0, 0);
    __builtin_amdgcn_s_setprio(0);
    if (st) asm volatile("s_waitcnt vmcnt(0)" ::: "memory");
    __builtin_amdgcn_s_barrier();  // publishes t+1's stages to all waves
  }

  // epilogue: Xh[bc][4+l][:] += C * gate[bc][:]  (rows: row = bc*29 + l)
#pragma unroll
  for (int mi = 0; mi < 8; mi++) {
#pragma unroll
    for (int r = 0; r < 4; r++) {
      int row = m0 + wm + mi * 16 + q * 4 + r;
      int bc = row / 29, l = row - bc * 29;
      long xbase = ((long)bc * 66 + 4 + l) * 1024 + imoff;
      const float* gp = gate + (long)bc * 1024;
#pragma unroll
      for (int ni = 0; ni < 4; ni++) {
        int col = n0 + wn + ni * 16 + mr;
        long x = xbase + col;
        XhMut[x] = (bf16_t)fmaf(acc[mi][ni][r], gp[col], (float)XhMut[x]);
      }
    }
  }
}

// ====================== MFMA flash attention ===============================
__global__ __launch_bounds__(256) void attn_mfma(const bf16_t* __restrict__ QKVr,
                                                 const bf16_t* __restrict__ QKVi,
                                                 bf16_t* __restrict__ Or_,
                                                 bf16_t* __restrict__ Oi_) {
  const int h = blockIdx.x;
  const int b = blockIdx.y >> 2, qt = blockIdx.y & 3;
  const bf16_t* QKV = blockIdx.z ? QKVi : QKVr;
  bf16_t* O = blockIdx.z ? Oi_ : Or_;
  const int kvh = h >> 2;
  const int tid = threadIdx.x;
  const int lane = tid & 63, wave = tid >> 6;
  const int mr = lane & 15, q4 = lane >> 4;

  __shared__ bf16_t Ks[64 * 72];
  __shared__ bf16_t Vt[64 * 72];
  __shared__ bf16_t Ps[4][16 * 72];

  bf16x8 af[2];
  {
    const bf16_t* qp =
        QKV + (long)(b * 256 + qt * 64 + wave * 16 + mr) * 1536 + h * 64;
    af[0] = *(const bf16x8*)(qp + q4 * 8);
    af[1] = *(const bf16x8*)(qp + 32 + q4 * 8);
  }
  f32x4 Oacc[4];
#pragma unroll
  for (int ni = 0; ni < 4; ni++) Oacc[ni] = (f32x4){0.f, 0.f, 0.f, 0.f};
  float mrow[4], lrow[4];
#pragma unroll
  for (int r = 0; r < 4; r++) { mrow[r] = -1e30f; lrow[r] = 0.f; }

  for (int kt = 0; kt <= qt; kt++) {
#pragma unroll
    for (int it = 0; it < 2; it++) {
      int idx = tid + it * 256;
      int key = idx >> 3, dg = idx & 7;
      const bf16_t* kp = QKV + (long)(b * 256 + kt * 64 + key) * 1536 + 1024 +
                         kvh * 64 + dg * 8;
      *(bf16x8*)&Ks[key * 72 + dg * 8] = *(const bf16x8*)kp;
      bf16x8 vv = *(const bf16x8*)(kp + 256);
#pragma unroll
      for (int j = 0; j < 8; j++) Vt[(dg * 8 + j) * 72 + key] = vv[j];
    }
    __syncthreads();

    f32x4 S[4];
#pragma unroll
    for (int ni = 0; ni < 4; ni++) {
      S[ni] = (f32x4){0.f, 0.f, 0.f, 0.f};
#pragma unroll
      for (int s = 0; s < 2; s++) {
        bf16x8 kb = *(const bf16x8*)&Ks[(ni * 16 + mr) * 72 + s * 32 + q4 * 8];
        S[ni] = __builtin_amdgcn_mfma_f32_16x16x32_bf16(af[s], kb, S[ni], 0, 0, 0);
      }
    }
#pragma unroll
    for (int ni = 0; ni < 4; ni++) {
#pragma unroll
      for (int r = 0; r < 4; r++) {
        float v = S[ni][r] * 0.125f;
        if (kt == qt) {
          int qrow = wave * 16 + q4 * 4 + r;
          int kcol = ni * 16 + mr;
          if ((qrow >> 2) < (kcol >> 2)) v = -1e30f;
        }
        S[ni][r] = v;
      }
    }
#pragma unroll
    for (int r = 0; r < 4; r++) {
      float mx = fmaxf(fmaxf(S[0][r], S[1][r]), fmaxf(S[2][r], S[3][r]));
#pragma unroll
      for (int off = 1; off < 16; off <<= 1) mx = fmaxf(mx, __shfl_xor(mx, off));
      float mn = fmaxf(mrow[r], mx);
      float sc = __expf(mrow[r] - mn);
      mrow[r] = mn;
      float rs = 0.f;
#pragma unroll
      for (int ni = 0; ni < 4; ni++) {
        float p = __expf(S[ni][r] - mn);
        rs += p;
        Ps[wave][(q4 * 4 + r) * 72 + ni * 16 + mr] = (bf16_t)p;
      }
#pragma unroll
      for (int off = 1; off < 16; off <<= 1) rs += __shfl_xor(rs, off);
      lrow[r] = lrow[r] * sc + rs;
#pragma unroll
      for (int ni = 0; ni < 4; ni++) Oacc[ni][r] *= sc;
    }
    bf16x8 pa[2];
    pa[0] = *(const bf16x8*)&Ps[wave][mr * 72 + q4 * 8];
    pa[1] = *(const bf16x8*)&Ps[wave][mr * 72 + 32 + q4 * 8];
#pragma unroll
    for (int ni = 0; ni < 4; ni++) {
#pragma unroll
      for (int s = 0; s < 2; s++) {
        bf16x8 vb = *(const bf16x8*)&Vt[(ni * 16 + mr) * 72 + s * 32 + q4 * 8];
        Oacc[ni] = __builtin_amdgcn_mfma_f32_16x16x32_bf16(pa[s], vb, Oacc[ni], 0, 0, 0);
      }
    }
    __syncthreads();
  }

#pragma unroll
  for (int r = 0; r < 4; r++) {
    float inv = 1.f / lrow[r];
    long row = b * 256 + qt * 64 + wave * 16 + q4 * 4 + r;
#pragma unroll
    for (int ni = 0; ni < 4; ni++)
      O[row * 1024 + h * 64 + ni * 16 + mr] = (bf16_t)(Oacc[ni][r] * inv);
  }
}

// ===================== depthwise causal conv + GELU ========================
__global__ __launch_bounds__(256) void dwconv_kernel(const bf16_t* __restrict__ Xh,
                                                     const float* __restrict__ dwr,
                                                     const float* __restrict__ dwi,
                                                     bf16_t* __restrict__ Gr,
                                                     bf16_t* __restrict__ Gi) {
  const int d = blockIdx.x * 256 + threadIdx.x;
  const int bc = blockIdx.y;
  const float* dw = blockIdx.z ? dwi : dwr;
  bf16_t* G = blockIdx.z ? Gi : Gr;
  const int imoff = blockIdx.z ? 33 * 1024 : 0;
  float w[7];
#pragma unroll
  for (int j = 0; j < 7; j++) w[j] = dw[d * 7 + j];
  float x[29];
#pragma unroll
  for (int l = 0; l < 29; l++)
    x[l] = (float)Xh[((long)bc * 66 + 4 + l) * 1024 + imoff + d];
#pragma unroll
  for (int l = 0; l < 29; l++) {
    float y = 0.f;
#pragma unroll
    for (int j = 0; j < 7; j++) {
      int src = l - 6 + j;
      if (src >= 0) y = fmaf(w[j], x[src], y);
    }
    float ge = 0.5f * y * (1.f + erff(y * 0.7071067811865475f));
    G[((long)bc * 29 + l) * 1024 + d] = (bf16_t)ge;
  }
}

// ======================= irfft via MFMA + fp32 low =========================
// out[bc*64+t][d] = sum_k T[t][k]*XhHigh[bc][k][d] (basis hi+res direct from
// global in frag layout) + fp32 low-bin part from Af (f=0..3) via Tlow.
// Block: one bc x 128 d-cols, 2 waves, 18KB LDS -> 8 blocks/CU. ALL 57
// column loads hoisted to registers (1 HBM round-trip).
__global__ __launch_bounds__(128) void irfft_mfma(
    const bf16_t* __restrict__ Xh, const float* __restrict__ Afr,
    const float* __restrict__ Afi, const bf16_t* __restrict__ bhi,
    const bf16_t* __restrict__ bres, const float* __restrict__ tlow,
    float* __restrict__ out) {
  const int bc = blockIdx.y;        // 0..255
  const int d0 = blockIdx.x * 128;  // 8 d-tiles
  const int tid = threadIdx.x;      // 0..127
  const int lane = tid & 63, wave = tid >> 6;
  const int mr = lane & 15, q = lane >> 4;
  const int wn = wave * 64;

  __shared__ bf16_t Bs[128 * 64];
  __shared__ float Tl[64 * 8];

  ((float4*)Tl)[tid] = ((const float4*)tlow)[tid];  // 128 x 16B = 2KB

  // B transpose-stage: thread owns d-column (d0+tid); rows k=0..56 map to
  // Xh rows 4..32 (real f=4..32) and 37..64 (imag f=4..31); 57..63 zero.
  // All 57 loads hoisted into registers before any ds_write.
  {
    const bf16_t* xc = Xh + (long)bc * 66 * 1024 + d0 + tid;
    bf16_t xv[57];
#pragma unroll
    for (int j = 0; j < 57; j++) {
      int row = (j < 29) ? (4 + j) : (8 + j);
      xv[j] = xc[(long)row * 1024];
    }
    const int sw = tid & 7;
#pragma unroll
    for (int g = 0; g < 8; g++) {
      bf16x8 v;
#pragma unroll
      for (int i = 0; i < 8; i++) {
        int j = g * 8 + i;
        v[i] = (j < 57) ? xv[j] : (bf16_t)0.f;
      }
      *(bf16x8*)&Bs[tid * 64 + ((g ^ sw) << 3)] = v;
    }
  }
  __syncthreads();  // ds_writes (and Tl) complete

  f32x4 acc[4][4];
#pragma unroll
  for (int i = 0; i < 4; i++)
#pragma unroll
    for (int j = 0; j < 4; j++) acc[i][j] = (f32x4){0.f, 0.f, 0.f, 0.f};

#pragma unroll
  for (int s = 0; s < 2; s++) {
    bf16x8 bfv[4];
#pragma unroll
    for (int ni = 0; ni < 4; ni++) {
      int dcol = wn + ni * 16 + mr;
      bfv[ni] = *(const bf16x8*)&Bs[dcol * 64 + (((s * 4 + q) ^ (dcol & 7)) << 3)];
    }
#pragma unroll
    for (int mi = 0; mi < 4; mi++) {
      int trow = mi * 16 + mr;
      bf16x8 ah = *(const bf16x8*)&bhi[trow * 64 + (s * 4 + q) * 8];
      bf16x8 ar = *(const bf16x8*)&bres[trow * 64 + (s * 4 + q) * 8];
#pragma unroll
      for (int ni = 0; ni < 4; ni++) {
        acc[mi][ni] = __builtin_amdgcn_mfma_f32_16x16x32_bf16(
            ah, bfv[ni], acc[mi][ni], 0, 0, 0);
        acc[mi][ni] = __builtin_amdgcn_mfma_f32_16x16x32_bf16(
            ar, bfv[ni], acc[mi][ni], 0, 0, 0);
      }
    }
  }

  // fp32 low-bin epilogue: rows f=0..3 of Af (alpha-fused), Tlow basis
  const int arow = (bc >> 6) * 256 + (bc & 63) * 4;
  float R[4][7];
#pragma unroll
  for (int ni = 0; ni < 4; ni++) {
    long ab = (long)arow * 1024 + d0 + wn + ni * 16 + mr;
    R[ni][0] = Afr[ab];
    R[ni][1] = Afr[ab + 1024];
    R[ni][2] = Afi[ab + 1024];
    R[ni][3] = Afr[ab + 2048];
    R[ni][4] = Afi[ab + 2048];
    R[ni][5] = Afr[ab + 3072];
    R[ni][6] = Afi[ab + 3072];
  }
  const long obase = ((long)bc * 64) * 1024 + d0;
#pragma unroll
  for (int mi = 0; mi < 4; mi++) {
#pragma unroll
    for (int r = 0; r < 4; r++) {
      int t = mi * 16 + q * 4 + r;
      const float* tl = &Tl[t * 8];
#pragma unroll
      for (int ni = 0; ni < 4; ni++) {
        float low = tl[0] * R[ni][0];
        low = fmaf(tl[1], R[ni][1], low);
        low = fmaf(tl[2], R[ni][2], low);
        low = fmaf(tl[3], R[ni][3], low);
        low = fmaf(tl[4], R[ni][4], low);
        low = fmaf(tl[5], R[ni][5], low);
        low = fmaf(tl[6], R[ni][6], low);
        out[obase + (long)t * 1024 + wn + ni * 16 + mr] = acc[mi][ni][r] + low;
      }
    }
  }
}

// ============================ launcher =====================================
extern "C" void kernel_launch(void* const* d_in, const int* in_sizes, int n_in,
                              void* d_out, int out_size, void* d_ws, size_t ws_size,
                              hipStream_t stream) {
  const float* hidden = (const float*)d_in[0];
  const float* q_w = (const float*)d_in[1];
  const float* k_w = (const float*)d_in[2];
  const float* v_w = (const float*)d_in[3];
  const float* o_w = (const float*)d_in[4];
  const float* dw_r = (const float*)d_in[5];
  const float* pw_r = (const float*)d_in[6];
  const float* dw_i = (const float*)d_in[7];
  const float* pw_i = (const float*)d_in[8];
  const float* gate_w = (const float*)d_in[9];
  const float* alpha_raw = (const float*)d_in[10];
  float* out = (float*)d_out;

  float* ws = (float*)d_ws;
  // fp32 region
  float* Afr = ws;                       // 1024*1024
  float* Afi = Afr + 1048576;
  float* gg = Afi + 1048576;             // 256*1024
  // bf16 region
  bf16_t* bws = (bf16_t*)(gg + 262144);
  bf16_t* Xh = bws;                      // 256*66*1024 = 17,301,504 bf16
  bf16_t* Wqkv_b = Xh + 17301504;        // 1536*1024
  bf16_t* ow_b = Wqkv_b + 1572864;       // 1024*1024
  bf16_t* gw_b = ow_b + 1048576;
  bf16_t* pwr_b = gw_b + 1048576;
  bf16_t* pwi_b = pwr_b + 1048576;
  bf16_t* XLr = pwi_b + 1048576;         // 1024*1024
  bf16_t* XLi = XLr + 1048576;
  bf16_t* gmean = XLi + 1048576;         // 256*1024
  bf16_t* QKVbr = gmean + 262144;        // 1024*1536
  bf16_t* QKVbi = QKVbr + 1572864;
  bf16_t* Obr = QKVbi + 1572864;         // 1024*1024
  bf16_t* Obi = Obr + 1048576;
  bf16_t* Gr = Obi + 1048576;            // 7424*1024
  bf16_t* Gi = Gr + 7602176;
  bf16_t* bhi = Gi + 7602176;            // 64*64 irfft basis hi (plain)
  bf16_t* bres = bhi + 4096;             // 64*64 irfft basis residual
  bf16_t* dbhi = bres + 4096;            // 80*64 dft basis hi (plain)
  bf16_t* dbres = dbhi + 5120;           // 80*64 dft basis residual
  float* tlowp = (float*)(dbres + 5120); // 64*8 fp32

  // 0) basis tables (plain frag layout)
  mk_basis<<<38, 256, 0, stream>>>(dbhi, dbres, bhi, bres, tlowp);
  // 1) rfft via MFMA -> bf16 Xh + bf16 X_low pack + bf16 chunk-mean
  dft_mfma<<<dim3(8, 256), 128, 0, stream>>>(hidden, dbhi, dbres, Xh, XLr,
                                             XLi, gmean);
  // 2) weights -> bf16 (single launch)
  prep_w<<<5632, 256, 0, stream>>>(q_w, k_w, v_w, o_w, gate_w, pw_r, pw_i,
                                   Wqkv_b, ow_b, gw_b, pwr_b, pwi_b);
  // 3) QKV projections (real & imag), bf16 out: M=1024, N=1536, 192 blocks
  gemm128<EP_NONE><<<192, 256, 0, stream>>>(
      XLr, XLi, Wqkv_b, Wqkv_b, 1536, 12, 2, QKVbr, QKVbi, nullptr, nullptr,
      nullptr);
  // 4) gate = sigmoid(mean @ gate_w^T): M=256, N=1024, 16 blocks
  gemm128<EP_SIGMOID><<<16, 256, 0, stream>>>(
      gmean, gmean, gw_b, gw_b, 1024, 8, 1, gg, gg, nullptr, nullptr,
      nullptr);
  // 5) MFMA flash attention (real & imag), bf16 O out
  attn_mfma<<<dim3(16, 16, 2), 256, 0, stream>>>(QKVbr, QKVbi, Obr, Obi);
  // 6) O projection + alpha*A_low + (1-alpha)*X_low -> fp32 Af: 128 blocks
  gemm128<EP_FUSELOW><<<128, 256, 0, stream>>>(
      Obr, Obi, ow_b, ow_b, 1024, 8, 2, Afr, Afi, XLr, XLi, alpha_raw);
  // 7) depthwise causal conv + exact GELU on high bins, bf16 out
  dwconv_kernel<<<dim3(4, 256, 2), 256, 0, stream>>>(Xh, dw_r, dw_i, Gr, Gi);
  // 8) pointwise conv + gate + residual, in-place into Xh high rows:
  //    8-phase 256^2 schedule
  gemm256_high<<<dim3(232), 512, 0, stream>>>(Gr, Gi, pwr_b, pwi_b, Xh, gg);
  // 9) irfft via MFMA + fp32 low-bin epilogue
  irfft_mfma<<<dim3(8, 256), 128, 0, stream>>>(Xh, Afr, Afi, bhi, bres,
                                               tlowp, out);
}